// Round 1
// baseline (515.717 us; speedup 1.0000x reference)
//
#include <hip/hip_runtime.h>

// Pin2PinAttraction: sum_i w[i] * ((x[a_i]-x[b_i])^2 + (y[a_i]-y[b_i])^2)
// pairs are interleaved [a0,b0,a1,b1,...], indices in [0, NUM_PINS).

__global__ __launch_bounds__(256) void p2p_attraction_kernel(
    const float* __restrict__ pin_pos,   // [2*num_pins]: x then y
    const float* __restrict__ weights,   // [num_pairs]
    const int*   __restrict__ pairs,     // [2*num_pairs] interleaved
    float*       __restrict__ out,       // [1]
    int num_pins,
    int num_pairs)
{
    const float* __restrict__ xs = pin_pos;
    const float* __restrict__ ys = pin_pos + num_pins;

    const int tid    = blockIdx.x * blockDim.x + threadIdx.x;
    const int stride = gridDim.x * blockDim.x;

    float acc = 0.0f;

    // 2 pairs per iteration: int4 of indices + float2 of weights (coalesced 16B/8B)
    const int4*   __restrict__ pairs4 = (const int4*)pairs;
    const float2* __restrict__ w2     = (const float2*)weights;
    const int n2 = num_pairs >> 1;

    for (int i = tid; i < n2; i += stride) {
        int4   p = pairs4[i];
        float2 w = w2[i];

        float xa0 = xs[p.x], xb0 = xs[p.y];
        float ya0 = ys[p.x], yb0 = ys[p.y];
        float xa1 = xs[p.z], xb1 = xs[p.w];
        float ya1 = ys[p.z], yb1 = ys[p.w];

        float dx0 = xa0 - xb0, dy0 = ya0 - yb0;
        float dx1 = xa1 - xb1, dy1 = ya1 - yb1;

        acc += w.x * (dx0 * dx0 + dy0 * dy0);
        acc += w.y * (dx1 * dx1 + dy1 * dy1);
    }

    // tail (odd num_pairs) — not hit for 8M but keep correct
    if ((num_pairs & 1) && tid == 0) {
        int a = pairs[2 * (num_pairs - 1)];
        int b = pairs[2 * (num_pairs - 1) + 1];
        float dx = xs[a] - xs[b];
        float dy = ys[a] - ys[b];
        acc += weights[num_pairs - 1] * (dx * dx + dy * dy);
    }

    // wave-64 butterfly reduce
    for (int off = 32; off > 0; off >>= 1)
        acc += __shfl_down(acc, off, 64);

    __shared__ float wave_sums[4];  // 256 threads = 4 waves
    const int lane = threadIdx.x & 63;
    const int wid  = threadIdx.x >> 6;
    if (lane == 0) wave_sums[wid] = acc;
    __syncthreads();

    if (threadIdx.x == 0) {
        float s = wave_sums[0] + wave_sums[1] + wave_sums[2] + wave_sums[3];
        atomicAdd(out, s);
    }
}

extern "C" void kernel_launch(void* const* d_in, const int* in_sizes, int n_in,
                              void* d_out, int out_size, void* d_ws, size_t ws_size,
                              hipStream_t stream) {
    const float* pin_pos = (const float*)d_in[0];
    const float* weights = (const float*)d_in[1];
    const int*   pairs   = (const int*)d_in[2];
    // d_in[3] = pin_mask (unused by reference)

    const int num_pins  = in_sizes[0] / 2;
    const int num_pairs = in_sizes[1];

    float* out = (float*)d_out;

    // d_out is poisoned to 0xAA before every timed launch — zero it (capturable).
    hipMemsetAsync(out, 0, sizeof(float), stream);

    const int block = 256;
    const int grid  = 2048;  // ~524k threads, grid-stride over 4M iter units
    p2p_attraction_kernel<<<grid, block, 0, stream>>>(
        pin_pos, weights, pairs, out, num_pins, num_pairs);
}

// Round 3
// 333.983 us; speedup vs baseline: 1.5441x; 1.5441x over previous
//
#include <hip/hip_runtime.h>

// Pin2PinAttraction: sum_i w[i] * ((x[a_i]-x[b_i])^2 + (y[a_i]-y[b_i])^2)
// pairs interleaved [a0,b0,a1,b1,...], indices in [0, num_pins).
//
// Strategy: repack x/y (8 MB apart, 2 lines per pin) into interleaved
// float2 xy[] in d_ws -> each index is ONE 8B gather from one line.
// Stream pairs/weights non-temporally to preserve L2 for the xy table.

typedef int   i32x4 __attribute__((ext_vector_type(4)));
typedef float f32x2 __attribute__((ext_vector_type(2)));

__global__ __launch_bounds__(256) void pack_xy_kernel(
    const float* __restrict__ pin_pos,
    f32x2*       __restrict__ xy,
    int num_pins)
{
    const int tid    = blockIdx.x * blockDim.x + threadIdx.x;
    const int stride = gridDim.x * blockDim.x;
    const float* __restrict__ xs = pin_pos;
    const float* __restrict__ ys = pin_pos + num_pins;
    for (int i = tid; i < num_pins; i += stride) {
        f32x2 v;
        v.x = xs[i];
        v.y = ys[i];
        xy[i] = v;
    }
}

__global__ __launch_bounds__(256) void p2p_gather_kernel(
    const f32x2* __restrict__ xy,      // [num_pins] packed {x,y}
    const float* __restrict__ weights, // [num_pairs]
    const int*   __restrict__ pairs,   // [2*num_pairs] interleaved
    float*       __restrict__ out,     // [1]
    int num_pairs)
{
    const int tid    = blockIdx.x * blockDim.x + threadIdx.x;
    const int stride = gridDim.x * blockDim.x;

    float acc = 0.0f;

    const i32x4* __restrict__ pairs4 = (const i32x4*)pairs;
    const f32x2* __restrict__ w2     = (const f32x2*)weights;
    const int n2 = num_pairs >> 1;

    for (int i = tid; i < n2; i += stride) {
        // streamed, read-once: non-temporal so they don't evict xy from L2
        i32x4 p = __builtin_nontemporal_load(pairs4 + i);
        f32x2 w = __builtin_nontemporal_load(w2 + i);

        f32x2 A0 = xy[p.x];
        f32x2 B0 = xy[p.y];
        f32x2 A1 = xy[p.z];
        f32x2 B1 = xy[p.w];

        float dx0 = A0.x - B0.x, dy0 = A0.y - B0.y;
        float dx1 = A1.x - B1.x, dy1 = A1.y - B1.y;

        acc += w.x * (dx0 * dx0 + dy0 * dy0);
        acc += w.y * (dx1 * dx1 + dy1 * dy1);
    }

    // tail (odd num_pairs) — not hit for 8M but keep correct
    if ((num_pairs & 1) && tid == 0) {
        int a = pairs[2 * (num_pairs - 1)];
        int b = pairs[2 * (num_pairs - 1) + 1];
        f32x2 A = xy[a], B = xy[b];
        float dx = A.x - B.x, dy = A.y - B.y;
        acc += weights[num_pairs - 1] * (dx * dx + dy * dy);
    }

    // wave-64 butterfly reduce
    for (int off = 32; off > 0; off >>= 1)
        acc += __shfl_down(acc, off, 64);

    __shared__ float wave_sums[4];  // 256 threads = 4 waves
    const int lane = threadIdx.x & 63;
    const int wid  = threadIdx.x >> 6;
    if (lane == 0) wave_sums[wid] = acc;
    __syncthreads();

    if (threadIdx.x == 0) {
        float s = wave_sums[0] + wave_sums[1] + wave_sums[2] + wave_sums[3];
        atomicAdd(out, s);
    }
}

// Fallback (no workspace): original 4-gather kernel, kept for safety.
__global__ __launch_bounds__(256) void p2p_attraction_fallback(
    const float* __restrict__ pin_pos,
    const float* __restrict__ weights,
    const int*   __restrict__ pairs,
    float*       __restrict__ out,
    int num_pins,
    int num_pairs)
{
    const float* __restrict__ xs = pin_pos;
    const float* __restrict__ ys = pin_pos + num_pins;
    const int tid    = blockIdx.x * blockDim.x + threadIdx.x;
    const int stride = gridDim.x * blockDim.x;
    float acc = 0.0f;
    const i32x4* __restrict__ pairs4 = (const i32x4*)pairs;
    const f32x2* __restrict__ w2     = (const f32x2*)weights;
    const int n2 = num_pairs >> 1;
    for (int i = tid; i < n2; i += stride) {
        i32x4 p = pairs4[i];
        f32x2 w = w2[i];
        float dx0 = xs[p.x] - xs[p.y], dy0 = ys[p.x] - ys[p.y];
        float dx1 = xs[p.z] - xs[p.w], dy1 = ys[p.z] - ys[p.w];
        acc += w.x * (dx0 * dx0 + dy0 * dy0);
        acc += w.y * (dx1 * dx1 + dy1 * dy1);
    }
    if ((num_pairs & 1) && tid == 0) {
        int a = pairs[2 * (num_pairs - 1)];
        int b = pairs[2 * (num_pairs - 1) + 1];
        float dx = xs[a] - xs[b], dy = ys[a] - ys[b];
        acc += weights[num_pairs - 1] * (dx * dx + dy * dy);
    }
    for (int off = 32; off > 0; off >>= 1)
        acc += __shfl_down(acc, off, 64);
    __shared__ float wave_sums[4];
    const int lane = threadIdx.x & 63;
    const int wid  = threadIdx.x >> 6;
    if (lane == 0) wave_sums[wid] = acc;
    __syncthreads();
    if (threadIdx.x == 0) {
        float s = wave_sums[0] + wave_sums[1] + wave_sums[2] + wave_sums[3];
        atomicAdd(out, s);
    }
}

extern "C" void kernel_launch(void* const* d_in, const int* in_sizes, int n_in,
                              void* d_out, int out_size, void* d_ws, size_t ws_size,
                              hipStream_t stream) {
    const float* pin_pos = (const float*)d_in[0];
    const float* weights = (const float*)d_in[1];
    const int*   pairs   = (const int*)d_in[2];
    // d_in[3] = pin_mask (unused by reference)

    const int num_pins  = in_sizes[0] / 2;
    const int num_pairs = in_sizes[1];

    float* out = (float*)d_out;

    // d_out is poisoned to 0xAA before every timed launch — zero it (capturable).
    hipMemsetAsync(out, 0, sizeof(float), stream);

    const int block = 256;
    const int grid  = 2048;  // 524k threads = full wave capacity at 256/block

    const size_t xy_bytes = (size_t)num_pins * sizeof(f32x2);
    if (ws_size >= xy_bytes) {
        f32x2* xy = (f32x2*)d_ws;
        pack_xy_kernel<<<grid, block, 0, stream>>>(pin_pos, xy, num_pins);
        p2p_gather_kernel<<<grid, block, 0, stream>>>(
            xy, weights, pairs, out, num_pairs);
    } else {
        p2p_attraction_fallback<<<grid, block, 0, stream>>>(
            pin_pos, weights, pairs, out, num_pins, num_pairs);
    }
}